// Round 1
// baseline (457.743 us; speedup 1.0000x reference)
//
#include <hip/hip_runtime.h>
#include <stdint.h>

#define B_ 4
#define S_ 1024
#define D_ 2048
#define H_ 16
#define HD 128
#define E_ 6144

typedef short bf16x8 __attribute__((ext_vector_type(8)));
typedef float f32x4 __attribute__((ext_vector_type(4)));

__device__ __forceinline__ unsigned short f2bf(float f) {
  union { float f; unsigned u; } x; x.f = f;
  unsigned r = x.u + 0x7fffu + ((x.u >> 16) & 1u);
  return (unsigned short)(r >> 16);
}

__device__ __forceinline__ void gl_lds16(const void* g, void* l) {
  __builtin_amdgcn_global_load_lds(
      (const __attribute__((address_space(1))) void*)g,
      (__attribute__((address_space(3))) void*)l, 16, 0, 0);
}

// ---------------- convert fp32 -> bf16 (vectorized) ----------------
__global__ __launch_bounds__(256) void cvt_bf16(const float* __restrict__ s,
                                                short* __restrict__ d, int n) {
  int i = (blockIdx.x * 256 + threadIdx.x) * 4;
  if (i >= n) return;
  float4 v = *(const float4*)(s + i);
  short4 o = make_short4((short)f2bf(v.x), (short)f2bf(v.y),
                         (short)f2bf(v.z), (short)f2bf(v.w));
  *(short4*)(d + i) = o;
}

// ---------------- RoPE cos/sin table: [s][j] j in [0,64) ----------------
__global__ __launch_bounds__(256) void rope_tbl(float2* __restrict__ t) {
  int idx = blockIdx.x * 256 + threadIdx.x;  // 65536
  int s = idx >> 6, j = idx & 63;
  // inv_freq = 10000^(-j/64) = 2^(-j*log2(10000)/64)
  float inv = exp2f(-0.20762050593045953f * (float)j);
  float a = (float)s * inv;
  t[idx] = make_float2(cosf(a), sinf(a));
}

// ---------------- QKV GEMM + bias + RoPE + scatter ----------------
// 128x128 tile, BK=32, 4 waves x (32 rows x 128 cols), 16x16x32 bf16 MFMA.
// Fragment-major LDS: chunk = ((frag_id)*4 + quad)*16 + col  (8 elems/chunk)
__global__ __launch_bounds__(256) void qkv_gemm(
    const short* __restrict__ Xb, const short* __restrict__ Wb,
    const float* __restrict__ bq, const float2* __restrict__ rope,
    short* __restrict__ Qg, short* __restrict__ Kg, short* __restrict__ Vtg) {
  __shared__ __align__(16) short smem[16896];  // As(4096) + Bs(4096); epilogue reuses 128x132
  short* As = smem;
  short* Bs = smem + 4096;

  const int tid = threadIdx.x;
  const int w = tid >> 6, lane = tid & 63;
  const int q = lane >> 4, c = lane & 15;
  const int bn = blockIdx.x, bm = blockIdx.y;
  const int r0 = bm * 128, c0 = bn * 128;

  const short* Ag = Xb + (size_t)r0 * D_;
  const short* Bg = Wb + (size_t)c0 * D_;

  int aoff[2], boff[2];
#pragma unroll
  for (int i = 0; i < 2; i++) {
    int ch = i * 256 + tid;
    int cc = ch & 15, qq = (ch >> 4) & 3;
    int tt = (ch >> 6) & 1, ww = (ch >> 7) & 3;
    aoff[i] = (ww * 32 + tt * 16 + cc) * D_ + qq * 8;
    int tjb = (ch >> 6) & 7;
    boff[i] = (tjb * 16 + cc) * D_ + qq * 8;
  }

  f32x4 acc[2][8];
#pragma unroll
  for (int ti = 0; ti < 2; ti++)
#pragma unroll
    for (int tj = 0; tj < 8; tj++) acc[ti][tj] = (f32x4){0.f, 0.f, 0.f, 0.f};

  for (int k = 0; k < D_; k += 32) {
#pragma unroll
    for (int i = 0; i < 2; i++) {
      int ch = i * 256 + tid;
      gl_lds16(Ag + aoff[i] + k, As + ch * 8);
      gl_lds16(Bg + boff[i] + k, Bs + ch * 8);
    }
    __syncthreads();
    bf16x8 a0 = *(const bf16x8*)(As + (w * 2 + 0) * 512 + lane * 8);
    bf16x8 a1 = *(const bf16x8*)(As + (w * 2 + 1) * 512 + lane * 8);
#pragma unroll
    for (int tj = 0; tj < 8; tj++) {
      bf16x8 bb = *(const bf16x8*)(Bs + tj * 512 + lane * 8);
      acc[0][tj] = __builtin_amdgcn_mfma_f32_16x16x32_bf16(a0, bb, acc[0][tj], 0, 0, 0);
      acc[1][tj] = __builtin_amdgcn_mfma_f32_16x16x32_bf16(a1, bb, acc[1][tj], 0, 0, 0);
    }
    __syncthreads();
  }

  const int head = bn / 3, typ = bn % 3;  // N-tile == one of q/k/v of one head
  const int b = r0 >> 10, s0 = r0 & 1023;

  float bias[8];
#pragma unroll
  for (int tj = 0; tj < 8; tj++) bias[tj] = bq[c0 + tj * 16 + c];
#pragma unroll
  for (int ti = 0; ti < 2; ti++)
#pragma unroll
    for (int tj = 0; tj < 8; tj++)
#pragma unroll
      for (int r = 0; r < 4; r++) acc[ti][tj][r] += bias[tj];

  if (typ < 2) {
    // RoPE: pair (d, d+64) == (tj, tj+4) in the same lane
#pragma unroll
    for (int ti = 0; ti < 2; ti++)
#pragma unroll
      for (int r = 0; r < 4; r++) {
        int s = s0 + w * 32 + ti * 16 + q * 4 + r;
#pragma unroll
        for (int tj = 0; tj < 4; tj++) {
          float2 cs = rope[s * 64 + tj * 16 + c];
          float x1 = acc[ti][tj][r], x2 = acc[ti][tj + 4][r];
          acc[ti][tj][r] = x1 * cs.x - x2 * cs.y;
          acc[ti][tj + 4][r] = x2 * cs.x + x1 * cs.y;
        }
      }
    const float scale = (typ == 0) ? 0.08838834764831845f : 1.0f;  // 1/sqrt(128) folded into Q
    short* dst = ((typ == 0) ? Qg : Kg) + (size_t)(b * H_ + head) * S_ * HD;
#pragma unroll
    for (int ti = 0; ti < 2; ti++)
#pragma unroll
      for (int r = 0; r < 4; r++) {
        int s = s0 + w * 32 + ti * 16 + q * 4 + r;
        short* row = dst + (size_t)s * HD;
#pragma unroll
        for (int tj = 0; tj < 8; tj++)
          row[tj * 16 + c] = (short)f2bf(acc[ti][tj][r] * scale);
      }
  } else {
    // V: transpose via LDS -> Vtg[bh][d][s]
    short* Vte = smem;  // 128 x 132 (pad +4 breaks bank aliasing)
#pragma unroll
    for (int ti = 0; ti < 2; ti++)
#pragma unroll
      for (int tj = 0; tj < 8; tj++) {
        int d = tj * 16 + c;
        int sl = w * 32 + ti * 16 + q * 4;
        short4 pk = make_short4((short)f2bf(acc[ti][tj][0]), (short)f2bf(acc[ti][tj][1]),
                                (short)f2bf(acc[ti][tj][2]), (short)f2bf(acc[ti][tj][3]));
        *(short4*)(Vte + d * 132 + sl) = pk;
      }
    __syncthreads();
    short* dst = Vtg + (size_t)(b * H_ + head) * HD * S_ + s0;
#pragma unroll
    for (int i = 0; i < 8; i++) {
      int f = i * 256 + tid;
      int d = f >> 4, sc = f & 15;
      short4 lo = *(const short4*)(Vte + d * 132 + sc * 8);
      short4 hi = *(const short4*)(Vte + d * 132 + sc * 8 + 4);
      short* g = dst + (size_t)d * S_ + sc * 8;
      *(short4*)(g) = lo;
      *(short4*)(g + 4) = hi;
    }
  }
}

// ---------------- causal flash attention ----------------
// block = (q-tile 128, head). KT=64. Q frags in regs; K/V staged fragment-major.
__global__ __launch_bounds__(256) void flash_attn(
    const short* __restrict__ Qg, const short* __restrict__ Kg,
    const short* __restrict__ Vtg, float* __restrict__ out) {
  __shared__ __align__(16) short Ks[8192];   // [ks4][tj4][q][c][8]
  __shared__ __align__(16) short Vts[8192];  // [ks2][tjd8][q][c][8]
  __shared__ __align__(16) short Ps[8192];   // [w][ti2][ks2][q][c][8]

  const int tid = threadIdx.x;
  const int w = tid >> 6, lane = tid & 63;
  const int q = lane >> 4, c = lane & 15;
  const int qt = blockIdx.x, bh = blockIdx.y;
  const int q0 = qt * 128;

  const short* Qh = Qg + (size_t)bh * S_ * HD;
  const short* Kh = Kg + (size_t)bh * S_ * HD;
  const short* Vh = Vtg + (size_t)bh * HD * S_;

  bf16x8 aq[2][4];
#pragma unroll
  for (int ti = 0; ti < 2; ti++)
#pragma unroll
    for (int ks = 0; ks < 4; ks++)
      aq[ti][ks] = *(const bf16x8*)(Qh + (size_t)(q0 + w * 32 + ti * 16 + c) * HD + ks * 32 + q * 8);

  f32x4 o[2][8];
  float m_[2][4], l_[2][4];
#pragma unroll
  for (int ti = 0; ti < 2; ti++) {
#pragma unroll
    for (int tj = 0; tj < 8; tj++) o[ti][tj] = (f32x4){0.f, 0.f, 0.f, 0.f};
#pragma unroll
    for (int r = 0; r < 4; r++) { m_[ti][r] = -1e30f; l_[ti][r] = 0.f; }
  }

  int koff[4], voff[4];
#pragma unroll
  for (int i = 0; i < 4; i++) {
    int ch = i * 256 + tid;
    int cc = ch & 15, qq = (ch >> 4) & 3;
    { int tj = (ch >> 6) & 3, ks = (ch >> 8) & 3;
      koff[i] = (tj * 16 + cc) * HD + ks * 32 + qq * 8; }
    { int tjd = (ch >> 6) & 7, ks = (ch >> 9) & 1;
      voff[i] = (tjd * 16 + cc) * S_ + ks * 32 + qq * 8; }
  }

  const int niter = 2 * qt + 2;
  for (int it = 0; it < niter; it++) {
    const int k0 = it * 64;
#pragma unroll
    for (int i = 0; i < 4; i++) {
      int ch = i * 256 + tid;
      gl_lds16(Kh + (size_t)k0 * HD + koff[i], Ks + ch * 8);
      gl_lds16(Vh + k0 + voff[i], Vts + ch * 8);
    }
    __syncthreads();

    f32x4 s[2][4];
#pragma unroll
    for (int ti = 0; ti < 2; ti++)
#pragma unroll
      for (int tj = 0; tj < 4; tj++) s[ti][tj] = (f32x4){0.f, 0.f, 0.f, 0.f};
#pragma unroll
    for (int ks = 0; ks < 4; ks++) {
#pragma unroll
      for (int tj = 0; tj < 4; tj++) {
        bf16x8 bk = *(const bf16x8*)(Ks + (ks * 4 + tj) * 512 + lane * 8);
        s[0][tj] = __builtin_amdgcn_mfma_f32_16x16x32_bf16(aq[0][ks], bk, s[0][tj], 0, 0, 0);
        s[1][tj] = __builtin_amdgcn_mfma_f32_16x16x32_bf16(aq[1][ks], bk, s[1][tj], 0, 0, 0);
      }
    }

    if (it >= 2 * qt) {  // diagonal tiles: causal mask
#pragma unroll
      for (int ti = 0; ti < 2; ti++)
#pragma unroll
        for (int tj = 0; tj < 4; tj++) {
          int kj = k0 + tj * 16 + c;
#pragma unroll
          for (int r = 0; r < 4; r++) {
            int qi = q0 + w * 32 + ti * 16 + q * 4 + r;
            if (kj > qi) s[ti][tj][r] = -1e30f;
          }
        }
    }

    // online softmax (row state lives replicated across the 16-lane col group)
#pragma unroll
    for (int ti = 0; ti < 2; ti++) {
#pragma unroll
      for (int r = 0; r < 4; r++) {
        float mx = fmaxf(fmaxf(s[ti][0][r], s[ti][1][r]), fmaxf(s[ti][2][r], s[ti][3][r]));
        mx = fmaxf(mx, __shfl_xor(mx, 1));
        mx = fmaxf(mx, __shfl_xor(mx, 2));
        mx = fmaxf(mx, __shfl_xor(mx, 4));
        mx = fmaxf(mx, __shfl_xor(mx, 8));
        float mn = fmaxf(m_[ti][r], mx);
        float alpha = __expf(m_[ti][r] - mn);
        m_[ti][r] = mn;
        float rs = 0.f;
#pragma unroll
        for (int tj = 0; tj < 4; tj++) {
          float e = __expf(s[ti][tj][r] - mn);
          s[ti][tj][r] = e;
          rs += e;
        }
        rs += __shfl_xor(rs, 1);
        rs += __shfl_xor(rs, 2);
        rs += __shfl_xor(rs, 4);
        rs += __shfl_xor(rs, 8);
        l_[ti][r] = l_[ti][r] * alpha + rs;
#pragma unroll
        for (int tj = 0; tj < 8; tj++) o[ti][tj][r] *= alpha;
      }
    }

    // P: C-layout regs -> fragment-major LDS (A-layout for PV)
#pragma unroll
    for (int ti = 0; ti < 2; ti++)
#pragma unroll
      for (int tj = 0; tj < 4; tj++) {
        int base = ((w * 2 + ti) * 2 + (tj >> 1)) * 512 +
                   (((tj * 2) + (c >> 3)) & 3) * 128 + (c & 7);
#pragma unroll
        for (int r = 0; r < 4; r++)
          Ps[base + (q * 4 + r) * 8] = (short)f2bf(s[ti][tj][r]);
      }
    __syncthreads();

#pragma unroll
    for (int ks = 0; ks < 2; ks++) {
      bf16x8 ap0 = *(const bf16x8*)(Ps + ((w * 2 + 0) * 2 + ks) * 512 + lane * 8);
      bf16x8 ap1 = *(const bf16x8*)(Ps + ((w * 2 + 1) * 2 + ks) * 512 + lane * 8);
#pragma unroll
      for (int tj = 0; tj < 8; tj++) {
        bf16x8 bv = *(const bf16x8*)(Vts + (ks * 8 + tj) * 512 + lane * 8);
        o[0][tj] = __builtin_amdgcn_mfma_f32_16x16x32_bf16(ap0, bv, o[0][tj], 0, 0, 0);
        o[1][tj] = __builtin_amdgcn_mfma_f32_16x16x32_bf16(ap1, bv, o[1][tj], 0, 0, 0);
      }
    }
    __syncthreads();  // protect Ks/Vts/Ps before next iteration's staging
  }

  const int b = bh >> 4, h = bh & 15;
#pragma unroll
  for (int ti = 0; ti < 2; ti++)
#pragma unroll
    for (int r = 0; r < 4; r++) {
      float inv = 1.0f / l_[ti][r];
      int sg = q0 + w * 32 + ti * 16 + q * 4 + r;
      float* dst = out + (size_t)(b * S_ + sg) * D_ + h * HD;
#pragma unroll
      for (int tj = 0; tj < 8; tj++) dst[tj * 16 + c] = o[ti][tj][r] * inv;
    }
}

extern "C" void kernel_launch(void* const* d_in, const int* in_sizes, int n_in,
                              void* d_out, int out_size, void* d_ws, size_t ws_size,
                              hipStream_t stream) {
  (void)in_sizes; (void)n_in; (void)out_size; (void)ws_size;
  const float* hs = (const float*)d_in[0];
  const float* wq = (const float*)d_in[1];
  const float* bq = (const float*)d_in[2];
  char* ws = (char*)d_ws;
  // workspace layout (bytes): Xb 16MiB | Wb 24MiB | Qg 16MiB | Kg 16MiB | Vtg 16MiB | rope 512KiB
  short* Xb = (short*)(ws);
  short* Wb = (short*)(ws + 16777216);
  short* Qg = (short*)(ws + 41943040);
  short* Kg = (short*)(ws + 58720256);
  short* Vtg = (short*)(ws + 75497472);
  float2* tbl = (float2*)(ws + 92274688);

  hipLaunchKernelGGL(cvt_bf16, dim3(8192), dim3(256), 0, stream, hs, Xb, B_ * S_ * D_);
  hipLaunchKernelGGL(cvt_bf16, dim3(12288), dim3(256), 0, stream, wq, Wb, E_ * D_);
  hipLaunchKernelGGL(rope_tbl, dim3(256), dim3(256), 0, stream, tbl);
  hipLaunchKernelGGL(qkv_gemm, dim3(48, 32), dim3(256), 0, stream, Xb, Wb, bq, tbl, Qg, Kg, Vtg);
  hipLaunchKernelGGL(flash_attn, dim3(8, 64), dim3(256), 0, stream, Qg, Kg, Vtg, (float*)d_out);
}

// Round 2
// 325.053 us; speedup vs baseline: 1.4082x; 1.4082x over previous
//
#include <hip/hip_runtime.h>
#include <stdint.h>

#define B_ 4
#define S_ 1024
#define D_ 2048
#define H_ 16
#define HD 128
#define E_ 6144

typedef short bf16x8 __attribute__((ext_vector_type(8)));
typedef float f32x4 __attribute__((ext_vector_type(4)));

__device__ __forceinline__ unsigned short f2bf(float f) {
  union { float f; unsigned u; } x; x.f = f;
  unsigned r = x.u + 0x7fffu + ((x.u >> 16) & 1u);
  return (unsigned short)(r >> 16);
}

__device__ __forceinline__ void gl_lds16(const void* g, void* l) {
  __builtin_amdgcn_global_load_lds(
      (const __attribute__((address_space(1))) void*)g,
      (__attribute__((address_space(3))) void*)l, 16, 0, 0);
}

// ---------- fp32 -> bf16 cast emitting the GEMM LDS-fragment-tiled layout ----
// out[tile = row>>7][ktile = k>>5][ ((rt*4+qq)*16+cc)*8 + j ]
// rt=(row>>4)&7, cc=row&15, qq=(k>>3)&3, j=k&7.  One 16-B write per thread.
__global__ __launch_bounds__(256) void cvt_tiled(const float* __restrict__ src,
                                                 short* __restrict__ dst) {
  int T = blockIdx.x * 256 + threadIdx.x;
  int row = T >> 8, kc = T & 255;  // kc: 8-elem chunk of k
  const float4* p = (const float4*)(src + ((size_t)row << 11) + (kc << 3));
  float4 v0 = p[0], v1 = p[1];
  int mt = row >> 7, rt = (row >> 4) & 7, cc = row & 15;
  int kt = kc >> 2, qq = kc & 3;
  union { short s[8]; int4 v; } u;
  u.s[0] = (short)f2bf(v0.x); u.s[1] = (short)f2bf(v0.y);
  u.s[2] = (short)f2bf(v0.z); u.s[3] = (short)f2bf(v0.w);
  u.s[4] = (short)f2bf(v1.x); u.s[5] = (short)f2bf(v1.y);
  u.s[6] = (short)f2bf(v1.z); u.s[7] = (short)f2bf(v1.w);
  *(int4*)(dst + (((size_t)(mt * 64 + kt)) << 12) + (((rt * 4 + qq) * 16 + cc) << 3)) = u.v;
}

// ---------------- RoPE cos/sin table ----------------
__global__ __launch_bounds__(256) void rope_tbl(float2* __restrict__ t) {
  int idx = blockIdx.x * 256 + threadIdx.x;  // 65536
  int s = idx >> 6, j = idx & 63;
  float inv = exp2f(-0.20762050593045953f * (float)j);
  float a = (float)s * inv;
  t[idx] = make_float2(cosf(a), sinf(a));
}

// ---------------- QKV GEMM + bias + RoPE + fragment-order scatter ----------
// 128x128 tile, BK=32, 2x2 waves of 64x64 (acc 4x4), contiguous staging.
__global__ __launch_bounds__(256) void qkv_gemm(
    const short* __restrict__ Xt, const short* __restrict__ Wt,
    const float* __restrict__ bq, const float2* __restrict__ rope,
    short* __restrict__ Qg, short* __restrict__ Kg, short* __restrict__ Vg) {
  __shared__ __align__(16) short As[4096];
  __shared__ __align__(16) short Bs[4096];

  const int tid = threadIdx.x;
  const int w = tid >> 6, lane = tid & 63;
  const int q = lane >> 4, c = lane & 15;
  const int wy = w >> 1, wx = w & 1;
  const int bn = blockIdx.x, bm = blockIdx.y;

  const short* Abase = Xt + (size_t)bm * 64 * 4096;
  const short* Bbase = Wt + (size_t)bn * 64 * 4096;

  f32x4 acc[4][4];
#pragma unroll
  for (int i = 0; i < 4; i++)
#pragma unroll
    for (int jl = 0; jl < 4; jl++) acc[i][jl] = (f32x4){0.f, 0.f, 0.f, 0.f};

  for (int kt = 0; kt < 64; kt++) {
    const short* Ak = Abase + (size_t)kt * 4096;
    const short* Bk = Bbase + (size_t)kt * 4096;
#pragma unroll
    for (int i = 0; i < 2; i++) {
      int ch = i * 256 + tid;
      gl_lds16(Ak + ch * 8, As + ch * 8);
      gl_lds16(Bk + ch * 8, Bs + ch * 8);
    }
    __syncthreads();
    bf16x8 a[4], b[4];
#pragma unroll
    for (int i = 0; i < 4; i++)
      a[i] = *(const bf16x8*)(As + (wy * 4 + i) * 512 + lane * 8);
#pragma unroll
    for (int jl = 0; jl < 4; jl++) {
      int ct = 2 * wx + (jl & 1) + ((jl >> 1) << 2);
      b[jl] = *(const bf16x8*)(Bs + ct * 512 + lane * 8);
    }
#pragma unroll
    for (int i = 0; i < 4; i++)
#pragma unroll
      for (int jl = 0; jl < 4; jl++)
        acc[i][jl] = __builtin_amdgcn_mfma_f32_16x16x32_bf16(a[i], b[jl], acc[i][jl], 0, 0, 0);
    __syncthreads();
  }

  const int head = bn / 3, typ = bn - head * 3;
  const int b = bm >> 3;
  const int bh = b * H_ + head;
  const int s0 = (bm & 7) << 7;

  int ctl[4];
  float bias[4];
#pragma unroll
  for (int jl = 0; jl < 4; jl++) {
    ctl[jl] = 2 * wx + (jl & 1) + ((jl >> 1) << 2);
    bias[jl] = bq[bn * 128 + ctl[jl] * 16 + c];
  }
#pragma unroll
  for (int i = 0; i < 4; i++)
#pragma unroll
    for (int jl = 0; jl < 4; jl++)
#pragma unroll
      for (int r = 0; r < 4; r++) acc[i][jl][r] += bias[jl];

  if (typ < 2) {
    // RoPE: pair (d, d+64) == (ctl[jl], ctl[jl]+4) == (jl, jl+2), same lane
#pragma unroll
    for (int i = 0; i < 4; i++)
#pragma unroll
      for (int r = 0; r < 4; r++) {
        int s = s0 + wy * 64 + i * 16 + q * 4 + r;
#pragma unroll
        for (int jl = 0; jl < 2; jl++) {
          float2 cs = rope[s * 64 + ctl[jl] * 16 + c];
          float x1 = acc[i][jl][r], x2 = acc[i][jl + 2][r];
          acc[i][jl][r] = x1 * cs.x - x2 * cs.y;
          acc[i][jl + 2][r] = x2 * cs.x + x1 * cs.y;
        }
      }
    if (typ == 0) {  // Q natural [bh][s][128], 1/sqrt(hd) folded in
      short* dst = Qg + (size_t)bh * S_ * HD;
#pragma unroll
      for (int i = 0; i < 4; i++)
#pragma unroll
        for (int r = 0; r < 4; r++) {
          int s = s0 + wy * 64 + i * 16 + q * 4 + r;
          short* row = dst + (size_t)s * HD;
#pragma unroll
          for (int jl = 0; jl < 4; jl++)
            row[ctl[jl] * 16 + c] = (short)f2bf(acc[i][jl][r] * 0.08838834764831845f);
        }
    } else {  // K in flash B-operand fragment order [bh][kt][8192]
      short* dst = Kg + (size_t)bh * 16 * 8192 + (size_t)((s0 >> 6) + wy) * 8192;
#pragma unroll
      for (int i = 0; i < 4; i++)
#pragma unroll
        for (int jl = 0; jl < 4; jl++) {
          int ks = ctl[jl] >> 1;
          int qqf = ((ctl[jl] & 1) << 1) + (c >> 3);
          short* p = dst + (ks * 4 + i) * 512 + qqf * 128 + (c & 7);
#pragma unroll
          for (int r = 0; r < 4; r++)
            p[(q * 4 + r) * 8] = (short)f2bf(acc[i][jl][r]);
        }
    }
  } else {  // V in flash B-operand (k = seq) fragment order [bh][kt][8192]
    short* dst = Vg + (size_t)bh * 16 * 8192 + (size_t)((s0 >> 6) + wy) * 8192;
#pragma unroll
    for (int i = 0; i < 4; i++)
#pragma unroll
      for (int jl = 0; jl < 4; jl++)
#pragma unroll
        for (int r = 0; r < 4; r++) {
          int sl = q * 4 + r;
          int qqf = ((i & 1) << 1) + (sl >> 3);
          dst[((i >> 1) * 8 + ctl[jl]) * 512 + qqf * 128 + c * 8 + (sl & 7)] =
              (short)f2bf(acc[i][jl][r]);
        }
  }
}

// ---------------- causal flash attention, q-tile 64, KT 64 ----------------
__global__ __launch_bounds__(256) void flash_attn(
    const short* __restrict__ Qg, const short* __restrict__ Kg,
    const short* __restrict__ Vg, float* __restrict__ out) {
  __shared__ __align__(16) short Ks[8192];
  __shared__ __align__(16) short Vts[8192];
  __shared__ __align__(16) short Ps[4096];  // wave-private 1024-short regions

  const int tid = threadIdx.x;
  const int w = tid >> 6, lane = tid & 63;
  const int q = lane >> 4, c = lane & 15;
  const int bh = blockIdx.x, qt = blockIdx.y;  // XCD = bh%8 -> balanced qt
  const int q0 = qt * 64;

  const short* Qh = Qg + (size_t)bh * S_ * HD;
  const short* Kh = Kg + (size_t)bh * 16 * 8192;
  const short* Vh = Vg + (size_t)bh * 16 * 8192;

  bf16x8 aq[4];  // wave w owns q-rows q0 + w*16 + [0,16)
#pragma unroll
  for (int ks = 0; ks < 4; ks++)
    aq[ks] = *(const bf16x8*)(Qh + (size_t)(q0 + w * 16 + c) * HD + ks * 32 + q * 8);

  f32x4 o[8];
  float m_[4], l_[4];
#pragma unroll
  for (int tj = 0; tj < 8; tj++) o[tj] = (f32x4){0.f, 0.f, 0.f, 0.f};
#pragma unroll
  for (int r = 0; r < 4; r++) { m_[r] = -1e30f; l_[r] = 0.f; }

  for (int it = 0; it <= qt; it++) {
#pragma unroll
    for (int i = 0; i < 4; i++) {
      int ch = i * 256 + tid;
      gl_lds16(Kh + (size_t)it * 8192 + ch * 8, Ks + ch * 8);
      gl_lds16(Vh + (size_t)it * 8192 + ch * 8, Vts + ch * 8);
    }
    __syncthreads();

    f32x4 s[4];
#pragma unroll
    for (int tj = 0; tj < 4; tj++) s[tj] = (f32x4){0.f, 0.f, 0.f, 0.f};
#pragma unroll
    for (int ks = 0; ks < 4; ks++)
#pragma unroll
      for (int tj = 0; tj < 4; tj++) {
        bf16x8 bk = *(const bf16x8*)(Ks + (ks * 4 + tj) * 512 + lane * 8);
        s[tj] = __builtin_amdgcn_mfma_f32_16x16x32_bf16(aq[ks], bk, s[tj], 0, 0, 0);
      }

    if (it == qt) {  // diagonal tile only
#pragma unroll
      for (int tj = 0; tj < 4; tj++) {
        int kj = tj * 16 + c;
#pragma unroll
        for (int r = 0; r < 4; r++)
          if (kj > w * 16 + q * 4 + r) s[tj][r] = -1e30f;
      }
    }

#pragma unroll
    for (int r = 0; r < 4; r++) {
      float mx = fmaxf(fmaxf(s[0][r], s[1][r]), fmaxf(s[2][r], s[3][r]));
      mx = fmaxf(mx, __shfl_xor(mx, 1));
      mx = fmaxf(mx, __shfl_xor(mx, 2));
      mx = fmaxf(mx, __shfl_xor(mx, 4));
      mx = fmaxf(mx, __shfl_xor(mx, 8));
      float mn = fmaxf(m_[r], mx);
      float alpha = __expf(m_[r] - mn);
      m_[r] = mn;
      float rs = 0.f;
#pragma unroll
      for (int tj = 0; tj < 4; tj++) {
        float e = __expf(s[tj][r] - mn);
        s[tj][r] = e;
        rs += e;
      }
      rs += __shfl_xor(rs, 1);
      rs += __shfl_xor(rs, 2);
      rs += __shfl_xor(rs, 4);
      rs += __shfl_xor(rs, 8);
      l_[r] = l_[r] * alpha + rs;
#pragma unroll
      for (int tjd = 0; tjd < 8; tjd++) o[tjd][r] *= alpha;
    }

    // P: C-layout -> wave-private A-layout region (no barrier needed)
#pragma unroll
    for (int tj = 0; tj < 4; tj++) {
      int base = w * 1024 + (tj >> 1) * 512 + (((tj & 1) << 1) + (c >> 3)) * 128 + (c & 7);
#pragma unroll
      for (int r = 0; r < 4; r++)
        Ps[base + (q * 4 + r) * 8] = (short)f2bf(s[tj][r]);
    }

#pragma unroll
    for (int ks2 = 0; ks2 < 2; ks2++) {
      bf16x8 ap = *(const bf16x8*)(Ps + w * 1024 + ks2 * 512 + lane * 8);
#pragma unroll
      for (int tjd = 0; tjd < 8; tjd++) {
        bf16x8 bv = *(const bf16x8*)(Vts + (ks2 * 8 + tjd) * 512 + lane * 8);
        o[tjd] = __builtin_amdgcn_mfma_f32_16x16x32_bf16(ap, bv, o[tjd], 0, 0, 0);
      }
    }
    __syncthreads();  // Ks/Vts consumed before next staging
  }

  const int b = bh >> 4, h = bh & 15;
#pragma unroll
  for (int r = 0; r < 4; r++) {
    float inv = 1.0f / l_[r];
    int sg = q0 + w * 16 + q * 4 + r;
    float* dst = out + (size_t)(b * S_ + sg) * D_ + h * HD;
#pragma unroll
    for (int tjd = 0; tjd < 8; tjd++) dst[tjd * 16 + c] = o[tjd][r] * inv;
  }
}

extern "C" void kernel_launch(void* const* d_in, const int* in_sizes, int n_in,
                              void* d_out, int out_size, void* d_ws, size_t ws_size,
                              hipStream_t stream) {
  (void)in_sizes; (void)n_in; (void)out_size; (void)ws_size;
  const float* hs = (const float*)d_in[0];
  const float* wq = (const float*)d_in[1];
  const float* bq = (const float*)d_in[2];
  char* ws = (char*)d_ws;
  // ws: Xt 16MiB | Wt 24MiB | Qg 16MiB | Kg 16MiB | Vg 16MiB | rope 512KiB
  short* Xt = (short*)(ws);
  short* Wt = (short*)(ws + 16777216);
  short* Qg = (short*)(ws + 41943040);
  short* Kg = (short*)(ws + 58720256);
  short* Vg = (short*)(ws + 75497472);
  float2* tbl = (float2*)(ws + 92274688);

  hipLaunchKernelGGL(cvt_tiled, dim3(4096), dim3(256), 0, stream, hs, Xt);
  hipLaunchKernelGGL(cvt_tiled, dim3(6144), dim3(256), 0, stream, wq, Wt);
  hipLaunchKernelGGL(rope_tbl, dim3(256), dim3(256), 0, stream, tbl);
  hipLaunchKernelGGL(qkv_gemm, dim3(48, 32), dim3(256), 0, stream, Xt, Wt, bq, tbl, Qg, Kg, Vg);
  hipLaunchKernelGGL(flash_attn, dim3(64, 16), dim3(256), 0, stream, Qg, Kg, Vg, (float*)d_out);
}

// Round 3
// 319.838 us; speedup vs baseline: 1.4312x; 1.0163x over previous
//
#include <hip/hip_runtime.h>
#include <stdint.h>

#define B_ 4
#define S_ 1024
#define D_ 2048
#define H_ 16
#define HD 128
#define E_ 6144

typedef short bf16x8 __attribute__((ext_vector_type(8)));
typedef float f32x4 __attribute__((ext_vector_type(4)));

__device__ __forceinline__ unsigned short f2bf(float f) {
  union { float f; unsigned u; } x; x.f = f;
  unsigned r = x.u + 0x7fffu + ((x.u >> 16) & 1u);
  return (unsigned short)(r >> 16);
}

__device__ __forceinline__ void gl_lds16(const void* g, void* l) {
  __builtin_amdgcn_global_load_lds(
      (const __attribute__((address_space(1))) void*)g,
      (__attribute__((address_space(3))) void*)l, 16, 0, 0);
}

// DPP cross-lane within the 16-lane row: single-cycle VALU, no LDS pipe.
template <int C>
__device__ __forceinline__ float dppf(float x) {
  union { float f; int i; } u; u.f = x;
  u.i = __builtin_amdgcn_update_dpp(u.i, u.i, C, 0xF, 0xF, true);
  return u.f;
}
__device__ __forceinline__ float red_max16(float v) {
  v = fmaxf(v, dppf<0xB1>(v));   // quad_perm [1,0,3,2]  (xor 1)
  v = fmaxf(v, dppf<0x4E>(v));   // quad_perm [2,3,0,1]  (xor 2)
  v = fmaxf(v, dppf<0x124>(v));  // row_ror:4
  v = fmaxf(v, dppf<0x128>(v));  // row_ror:8
  return v;
}
__device__ __forceinline__ float red_sum16(float v) {
  v += dppf<0xB1>(v);
  v += dppf<0x4E>(v);
  v += dppf<0x124>(v);
  v += dppf<0x128>(v);
  return v;
}

// ---------- fp32 -> bf16 cast emitting the GEMM LDS-fragment-tiled layout ----
__global__ __launch_bounds__(256) void cvt_tiled(const float* __restrict__ src,
                                                 short* __restrict__ dst) {
  int T = blockIdx.x * 256 + threadIdx.x;
  int row = T >> 8, kc = T & 255;
  const float4* p = (const float4*)(src + ((size_t)row << 11) + (kc << 3));
  float4 v0 = p[0], v1 = p[1];
  int mt = row >> 7, rt = (row >> 4) & 7, cc = row & 15;
  int kt = kc >> 2, qq = kc & 3;
  union { short s[8]; int4 v; } u;
  u.s[0] = (short)f2bf(v0.x); u.s[1] = (short)f2bf(v0.y);
  u.s[2] = (short)f2bf(v0.z); u.s[3] = (short)f2bf(v0.w);
  u.s[4] = (short)f2bf(v1.x); u.s[5] = (short)f2bf(v1.y);
  u.s[6] = (short)f2bf(v1.z); u.s[7] = (short)f2bf(v1.w);
  *(int4*)(dst + (((size_t)(mt * 64 + kt)) << 12) + (((rt * 4 + qq) * 16 + cc) << 3)) = u.v;
}

// ---------------- RoPE cos/sin table ----------------
__global__ __launch_bounds__(256) void rope_tbl(float2* __restrict__ t) {
  int idx = blockIdx.x * 256 + threadIdx.x;  // 65536
  int s = idx >> 6, j = idx & 63;
  float inv = exp2f(-0.20762050593045953f * (float)j);
  float a = (float)s * inv;
  t[idx] = make_float2(cosf(a), sinf(a));
}

// ---------------- QKV GEMM + bias + RoPE + fragment-order scatter ----------
// 128x128 tile, BK=64 (32 MFMA per barrier pair), 2x2 waves of 64x64.
__global__ __launch_bounds__(256) void qkv_gemm(
    const short* __restrict__ Xt, const short* __restrict__ Wt,
    const float* __restrict__ bq, const float2* __restrict__ rope,
    short* __restrict__ Qg, short* __restrict__ Kg, short* __restrict__ Vg) {
  __shared__ __align__(16) short As[8192];
  __shared__ __align__(16) short Bs[8192];

  const int tid = threadIdx.x;
  const int w = tid >> 6, lane = tid & 63;
  const int q = lane >> 4, c = lane & 15;
  const int wy = w >> 1, wx = w & 1;
  const int bn = blockIdx.x, bm = blockIdx.y;

  const short* Abase = Xt + (size_t)bm * 64 * 4096;
  const short* Bbase = Wt + (size_t)bn * 64 * 4096;

  f32x4 acc[4][4];
#pragma unroll
  for (int i = 0; i < 4; i++)
#pragma unroll
    for (int jl = 0; jl < 4; jl++) acc[i][jl] = (f32x4){0.f, 0.f, 0.f, 0.f};

  for (int kt = 0; kt < 32; kt++) {
    const short* Ak = Abase + (size_t)kt * 8192;
    const short* Bk = Bbase + (size_t)kt * 8192;
#pragma unroll
    for (int i = 0; i < 4; i++) {
      int ch = i * 256 + tid;
      gl_lds16(Ak + ch * 8, As + ch * 8);
      gl_lds16(Bk + ch * 8, Bs + ch * 8);
    }
    __syncthreads();
#pragma unroll
    for (int ss = 0; ss < 2; ss++) {
      const short* Asub = As + ss * 4096;
      const short* Bsub = Bs + ss * 4096;
      bf16x8 a[4], b[4];
#pragma unroll
      for (int i = 0; i < 4; i++)
        a[i] = *(const bf16x8*)(Asub + (wy * 4 + i) * 512 + lane * 8);
#pragma unroll
      for (int jl = 0; jl < 4; jl++) {
        int ct = 2 * wx + (jl & 1) + ((jl >> 1) << 2);
        b[jl] = *(const bf16x8*)(Bsub + ct * 512 + lane * 8);
      }
#pragma unroll
      for (int i = 0; i < 4; i++)
#pragma unroll
        for (int jl = 0; jl < 4; jl++)
          acc[i][jl] = __builtin_amdgcn_mfma_f32_16x16x32_bf16(a[i], b[jl], acc[i][jl], 0, 0, 0);
    }
    __syncthreads();
  }

  const int head = bn / 3, typ = bn - head * 3;
  const int b = bm >> 3;
  const int bh = b * H_ + head;
  const int s0 = (bm & 7) << 7;

  int ctl[4];
  float bias[4];
#pragma unroll
  for (int jl = 0; jl < 4; jl++) {
    ctl[jl] = 2 * wx + (jl & 1) + ((jl >> 1) << 2);
    bias[jl] = bq[bn * 128 + ctl[jl] * 16 + c];
  }
#pragma unroll
  for (int i = 0; i < 4; i++)
#pragma unroll
    for (int jl = 0; jl < 4; jl++)
#pragma unroll
      for (int r = 0; r < 4; r++) acc[i][jl][r] += bias[jl];

  if (typ < 2) {
    // RoPE: pair (d, d+64) == (ctl[jl], ctl[jl]+4) == (jl, jl+2), same lane
#pragma unroll
    for (int i = 0; i < 4; i++)
#pragma unroll
      for (int r = 0; r < 4; r++) {
        int s = s0 + wy * 64 + i * 16 + q * 4 + r;
#pragma unroll
        for (int jl = 0; jl < 2; jl++) {
          float2 cs = rope[s * 64 + ctl[jl] * 16 + c];
          float x1 = acc[i][jl][r], x2 = acc[i][jl + 2][r];
          acc[i][jl][r] = x1 * cs.x - x2 * cs.y;
          acc[i][jl + 2][r] = x2 * cs.x + x1 * cs.y;
        }
      }
    if (typ == 0) {  // Q natural [bh][s][128], 1/sqrt(hd) folded in
      short* dst = Qg + (size_t)bh * S_ * HD;
#pragma unroll
      for (int i = 0; i < 4; i++)
#pragma unroll
        for (int r = 0; r < 4; r++) {
          int s = s0 + wy * 64 + i * 16 + q * 4 + r;
          short* row = dst + (size_t)s * HD;
#pragma unroll
          for (int jl = 0; jl < 4; jl++)
            row[ctl[jl] * 16 + c] = (short)f2bf(acc[i][jl][r] * 0.08838834764831845f);
        }
    } else {  // K in flash B-operand fragment order [bh][kt][8192]
      short* dst = Kg + (size_t)bh * 16 * 8192 + (size_t)((s0 >> 6) + wy) * 8192;
#pragma unroll
      for (int i = 0; i < 4; i++)
#pragma unroll
        for (int jl = 0; jl < 4; jl++) {
          int ks = ctl[jl] >> 1;
          int qqf = ((ctl[jl] & 1) << 1) + (c >> 3);
          short* p = dst + (ks * 4 + i) * 512 + qqf * 128 + (c & 7);
#pragma unroll
          for (int r = 0; r < 4; r++)
            p[(q * 4 + r) * 8] = (short)f2bf(acc[i][jl][r]);
        }
    }
  } else {  // V in flash B-operand (k = seq) fragment order [bh][kt][8192]
    short* dst = Vg + (size_t)bh * 16 * 8192 + (size_t)((s0 >> 6) + wy) * 8192;
#pragma unroll
    for (int i = 0; i < 4; i++)
#pragma unroll
      for (int jl = 0; jl < 4; jl++)
#pragma unroll
        for (int r = 0; r < 4; r++) {
          int sl = q * 4 + r;
          int qqf = ((i & 1) << 1) + (sl >> 3);
          dst[((i >> 1) * 8 + ctl[jl]) * 512 + qqf * 128 + c * 8 + (sl & 7)] =
              (short)f2bf(acc[i][jl][r]);
        }
  }
}

// ---------------- causal flash attention, q-tile 64, KT 64 ----------------
__global__ __launch_bounds__(256) void flash_attn(
    const short* __restrict__ Qg, const short* __restrict__ Kg,
    const short* __restrict__ Vg, float* __restrict__ out) {
  __shared__ __align__(16) short Ks[8192];
  __shared__ __align__(16) short Vts[8192];
  __shared__ __align__(16) short Ps[4096];  // wave-private 1024-short regions

  const int tid = threadIdx.x;
  const int w = tid >> 6, lane = tid & 63;
  const int q = lane >> 4, c = lane & 15;
  const int bh = blockIdx.x, qt = blockIdx.y;  // XCD = bh%8 -> balanced qt
  const int q0 = qt * 64;

  const short* Qh = Qg + (size_t)bh * S_ * HD;
  const short* Kh = Kg + (size_t)bh * 16 * 8192;
  const short* Vh = Vg + (size_t)bh * 16 * 8192;

  bf16x8 aq[4];  // wave w owns q-rows q0 + w*16 + [0,16)
#pragma unroll
  for (int ks = 0; ks < 4; ks++)
    aq[ks] = *(const bf16x8*)(Qh + (size_t)(q0 + w * 16 + c) * HD + ks * 32 + q * 8);

  f32x4 o[8];
  float m_[4], l_[4];
#pragma unroll
  for (int tj = 0; tj < 8; tj++) o[tj] = (f32x4){0.f, 0.f, 0.f, 0.f};
#pragma unroll
  for (int r = 0; r < 4; r++) { m_[r] = -1e30f; l_[r] = 0.f; }

  for (int it = 0; it <= qt; it++) {
#pragma unroll
    for (int i = 0; i < 4; i++) {
      int ch = i * 256 + tid;
      gl_lds16(Kh + (size_t)it * 8192 + ch * 8, Ks + ch * 8);
      gl_lds16(Vh + (size_t)it * 8192 + ch * 8, Vts + ch * 8);
    }
    __syncthreads();

    f32x4 s[4];
#pragma unroll
    for (int tj = 0; tj < 4; tj++) s[tj] = (f32x4){0.f, 0.f, 0.f, 0.f};
#pragma unroll
    for (int ks = 0; ks < 4; ks++)
#pragma unroll
      for (int tj = 0; tj < 4; tj++) {
        bf16x8 bk = *(const bf16x8*)(Ks + (ks * 4 + tj) * 512 + lane * 8);
        s[tj] = __builtin_amdgcn_mfma_f32_16x16x32_bf16(aq[ks], bk, s[tj], 0, 0, 0);
      }

    if (it == qt) {  // diagonal tile only
#pragma unroll
      for (int tj = 0; tj < 4; tj++) {
        int kj = tj * 16 + c;
#pragma unroll
        for (int r = 0; r < 4; r++)
          if (kj > w * 16 + q * 4 + r) s[tj][r] = -1e30f;
      }
    }

    // online softmax — all cross-lane via DPP (VALU pipe, no ds_bpermute)
#pragma unroll
    for (int r = 0; r < 4; r++) {
      float mx = fmaxf(fmaxf(s[0][r], s[1][r]), fmaxf(s[2][r], s[3][r]));
      mx = red_max16(mx);
      float mn = fmaxf(m_[r], mx);
      float alpha = __expf(m_[r] - mn);
      m_[r] = mn;
      float rs = 0.f;
#pragma unroll
      for (int tj = 0; tj < 4; tj++) {
        float e = __expf(s[tj][r] - mn);
        s[tj][r] = e;
        rs += e;
      }
      rs = red_sum16(rs);
      l_[r] = l_[r] * alpha + rs;
#pragma unroll
      for (int tjd = 0; tjd < 8; tjd++) o[tjd][r] *= alpha;
    }

    // P: C-layout -> wave-private A-layout region (no barrier needed)
#pragma unroll
    for (int tj = 0; tj < 4; tj++) {
      int base = w * 1024 + (tj >> 1) * 512 + (((tj & 1) << 1) + (c >> 3)) * 128 + (c & 7);
#pragma unroll
      for (int r = 0; r < 4; r++)
        Ps[base + (q * 4 + r) * 8] = (short)f2bf(s[tj][r]);
    }

#pragma unroll
    for (int ks2 = 0; ks2 < 2; ks2++) {
      bf16x8 ap = *(const bf16x8*)(Ps + w * 1024 + ks2 * 512 + lane * 8);
#pragma unroll
      for (int tjd = 0; tjd < 8; tjd++) {
        bf16x8 bv = *(const bf16x8*)(Vts + (ks2 * 8 + tjd) * 512 + lane * 8);
        o[tjd] = __builtin_amdgcn_mfma_f32_16x16x32_bf16(ap, bv, o[tjd], 0, 0, 0);
      }
    }
    __syncthreads();  // Ks/Vts consumed before next staging
  }

  const int b = bh >> 4, h = bh & 15;
#pragma unroll
  for (int r = 0; r < 4; r++) {
    float inv = 1.0f / l_[r];
    int sg = q0 + w * 16 + q * 4 + r;
    float* dst = out + (size_t)(b * S_ + sg) * D_ + h * HD;
#pragma unroll
    for (int tjd = 0; tjd < 8; tjd++) dst[tjd * 16 + c] = o[tjd][r] * inv;
  }
}

extern "C" void kernel_launch(void* const* d_in, const int* in_sizes, int n_in,
                              void* d_out, int out_size, void* d_ws, size_t ws_size,
                              hipStream_t stream) {
  (void)in_sizes; (void)n_in; (void)out_size; (void)ws_size;
  const float* hs = (const float*)d_in[0];
  const float* wq = (const float*)d_in[1];
  const float* bq = (const float*)d_in[2];
  char* ws = (char*)d_ws;
  // ws: Xt 16MiB | Wt 24MiB | Qg 16MiB | Kg 16MiB | Vg 16MiB | rope 512KiB
  short* Xt = (short*)(ws);
  short* Wt = (short*)(ws + 16777216);
  short* Qg = (short*)(ws + 41943040);
  short* Kg = (short*)(ws + 58720256);
  short* Vg = (short*)(ws + 75497472);
  float2* tbl = (float2*)(ws + 92274688);

  hipLaunchKernelGGL(cvt_tiled, dim3(4096), dim3(256), 0, stream, hs, Xt);
  hipLaunchKernelGGL(cvt_tiled, dim3(6144), dim3(256), 0, stream, wq, Wt);
  hipLaunchKernelGGL(rope_tbl, dim3(256), dim3(256), 0, stream, tbl);
  hipLaunchKernelGGL(qkv_gemm, dim3(48, 32), dim3(256), 0, stream, Xt, Wt, bq, tbl, Qg, Kg, Vg);
  hipLaunchKernelGGL(flash_attn, dim3(64, 16), dim3(256), 0, stream, Qg, Kg, Vg, (float*)d_out);
}

// Round 4
// 297.803 us; speedup vs baseline: 1.5371x; 1.0740x over previous
//
#include <hip/hip_runtime.h>
#include <stdint.h>

#define B_ 4
#define S_ 1024
#define D_ 2048
#define H_ 16
#define HD 128
#define E_ 6144

typedef short bf16x8 __attribute__((ext_vector_type(8)));
typedef float f32x4 __attribute__((ext_vector_type(4)));

__device__ __forceinline__ unsigned short f2bf(float f) {
  union { float f; unsigned u; } x; x.f = f;
  unsigned r = x.u + 0x7fffu + ((x.u >> 16) & 1u);
  return (unsigned short)(r >> 16);
}

__device__ __forceinline__ void gl_lds16(const void* g, void* l) {
  __builtin_amdgcn_global_load_lds(
      (const __attribute__((address_space(1))) void*)g,
      (__attribute__((address_space(3))) void*)l, 16, 0, 0);
}

// DPP cross-lane within the 16-lane row: single-cycle VALU, no LDS pipe.
template <int C>
__device__ __forceinline__ float dppf(float x) {
  union { float f; int i; } u; u.f = x;
  u.i = __builtin_amdgcn_update_dpp(u.i, u.i, C, 0xF, 0xF, true);
  return u.f;
}
__device__ __forceinline__ float red_max16(float v) {
  v = fmaxf(v, dppf<0xB1>(v));   // quad_perm [1,0,3,2]  (xor 1)
  v = fmaxf(v, dppf<0x4E>(v));   // quad_perm [2,3,0,1]  (xor 2)
  v = fmaxf(v, dppf<0x124>(v));  // row_ror:4
  v = fmaxf(v, dppf<0x128>(v));  // row_ror:8
  return v;
}
__device__ __forceinline__ float red_sum16(float v) {
  v += dppf<0xB1>(v);
  v += dppf<0x4E>(v);
  v += dppf<0x124>(v);
  v += dppf<0x128>(v);
  return v;
}

// ---- fp32 -> bf16 fragment-tiled cast via LDS repack ----
// One block per (mt, kt): 128 rows x 32 k -> one 8 KB contiguous output tile.
// Reads: 64 B/lane row segments (full sectors). Stores: 1 KiB/wave contiguous.
// LDS rows padded to 40 shorts (80 B): b128 read/write aliasing is 2-way max.
__global__ __launch_bounds__(256) void cvt_repack(const float* __restrict__ src,
                                                  short* __restrict__ dst) {
  __shared__ __align__(16) short L[128 * 40];
  const int tid = threadIdx.x;
  const int kt = blockIdx.x & 63, mt = blockIdx.x >> 6;

  // phase 1: coalesced read + convert + LDS write
  {
    int row = tid >> 1, half = tid & 1;
    const float* p = src + (size_t)(mt * 128 + row) * D_ + kt * 32 + half * 16;
    float4 v0 = *(const float4*)(p);
    float4 v1 = *(const float4*)(p + 4);
    float4 v2 = *(const float4*)(p + 8);
    float4 v3 = *(const float4*)(p + 12);
    union { short s[16]; int4 v[2]; } u;
    u.s[0] = (short)f2bf(v0.x);  u.s[1] = (short)f2bf(v0.y);
    u.s[2] = (short)f2bf(v0.z);  u.s[3] = (short)f2bf(v0.w);
    u.s[4] = (short)f2bf(v1.x);  u.s[5] = (short)f2bf(v1.y);
    u.s[6] = (short)f2bf(v1.z);  u.s[7] = (short)f2bf(v1.w);
    u.s[8] = (short)f2bf(v2.x);  u.s[9] = (short)f2bf(v2.y);
    u.s[10] = (short)f2bf(v2.z); u.s[11] = (short)f2bf(v2.w);
    u.s[12] = (short)f2bf(v3.x); u.s[13] = (short)f2bf(v3.y);
    u.s[14] = (short)f2bf(v3.z); u.s[15] = (short)f2bf(v3.w);
    int4* lp = (int4*)(L + row * 40 + half * 16);
    lp[0] = u.v[0];
    lp[1] = u.v[1];
  }
  __syncthreads();

  // phase 2: LDS fragment gather + contiguous global store
  short* out = dst + (((size_t)(mt * 64 + kt)) << 12);
#pragma unroll
  for (int i = 0; i < 2; i++) {
    int ch = i * 256 + tid;                  // 512 chunks x 8 shorts
    int cc = ch & 15, qq = (ch >> 4) & 3, rt = ch >> 6;
    int4 v = *(const int4*)(L + (rt * 16 + cc) * 40 + qq * 8);
    *(int4*)(out + ch * 8) = v;
  }
}

// ---------------- RoPE cos/sin table ----------------
__global__ __launch_bounds__(256) void rope_tbl(float2* __restrict__ t) {
  int idx = blockIdx.x * 256 + threadIdx.x;  // 65536
  int s = idx >> 6, j = idx & 63;
  float inv = exp2f(-0.20762050593045953f * (float)j);
  float a = (float)s * inv;
  t[idx] = make_float2(cosf(a), sinf(a));
}

// ---------------- QKV GEMM + bias + RoPE + fragment-order scatter ----------
// 128x128 tile, BK=32, 2x2 waves of 64x64 (acc 4x4), contiguous staging.
__global__ __launch_bounds__(256) void qkv_gemm(
    const short* __restrict__ Xt, const short* __restrict__ Wt,
    const float* __restrict__ bq, const float2* __restrict__ rope,
    short* __restrict__ Qg, short* __restrict__ Kg, short* __restrict__ Vg) {
  __shared__ __align__(16) short As[4096];
  __shared__ __align__(16) short Bs[4096];

  const int tid = threadIdx.x;
  const int w = tid >> 6, lane = tid & 63;
  const int q = lane >> 4, c = lane & 15;
  const int wy = w >> 1, wx = w & 1;
  const int bn = blockIdx.x, bm = blockIdx.y;

  const short* Abase = Xt + (size_t)bm * 64 * 4096;
  const short* Bbase = Wt + (size_t)bn * 64 * 4096;

  f32x4 acc[4][4];
#pragma unroll
  for (int i = 0; i < 4; i++)
#pragma unroll
    for (int jl = 0; jl < 4; jl++) acc[i][jl] = (f32x4){0.f, 0.f, 0.f, 0.f};

  for (int kt = 0; kt < 64; kt++) {
    const short* Ak = Abase + (size_t)kt * 4096;
    const short* Bk = Bbase + (size_t)kt * 4096;
#pragma unroll
    for (int i = 0; i < 2; i++) {
      int ch = i * 256 + tid;
      gl_lds16(Ak + ch * 8, As + ch * 8);
      gl_lds16(Bk + ch * 8, Bs + ch * 8);
    }
    __syncthreads();
    bf16x8 a[4], b[4];
#pragma unroll
    for (int i = 0; i < 4; i++)
      a[i] = *(const bf16x8*)(As + (wy * 4 + i) * 512 + lane * 8);
#pragma unroll
    for (int jl = 0; jl < 4; jl++) {
      int ct = 2 * wx + (jl & 1) + ((jl >> 1) << 2);
      b[jl] = *(const bf16x8*)(Bs + ct * 512 + lane * 8);
    }
#pragma unroll
    for (int i = 0; i < 4; i++)
#pragma unroll
      for (int jl = 0; jl < 4; jl++)
        acc[i][jl] = __builtin_amdgcn_mfma_f32_16x16x32_bf16(a[i], b[jl], acc[i][jl], 0, 0, 0);
    __syncthreads();
  }

  const int head = bn / 3, typ = bn - head * 3;
  const int b = bm >> 3;
  const int bh = b * H_ + head;
  const int s0 = (bm & 7) << 7;

  int ctl[4];
  float bias[4];
#pragma unroll
  for (int jl = 0; jl < 4; jl++) {
    ctl[jl] = 2 * wx + (jl & 1) + ((jl >> 1) << 2);
    bias[jl] = bq[bn * 128 + ctl[jl] * 16 + c];
  }
#pragma unroll
  for (int i = 0; i < 4; i++)
#pragma unroll
    for (int jl = 0; jl < 4; jl++)
#pragma unroll
      for (int r = 0; r < 4; r++) acc[i][jl][r] += bias[jl];

  if (typ < 2) {
    // RoPE: pair (d, d+64) == (ctl[jl], ctl[jl]+4) == (jl, jl+2), same lane
#pragma unroll
    for (int i = 0; i < 4; i++)
#pragma unroll
      for (int r = 0; r < 4; r++) {
        int s = s0 + wy * 64 + i * 16 + q * 4 + r;
#pragma unroll
        for (int jl = 0; jl < 2; jl++) {
          float2 cs = rope[s * 64 + ctl[jl] * 16 + c];
          float x1 = acc[i][jl][r], x2 = acc[i][jl + 2][r];
          acc[i][jl][r] = x1 * cs.x - x2 * cs.y;
          acc[i][jl + 2][r] = x2 * cs.x + x1 * cs.y;
        }
      }
    if (typ == 0) {  // Q natural [bh][s][128], 1/sqrt(hd) folded in
      short* dst = Qg + (size_t)bh * S_ * HD;
#pragma unroll
      for (int i = 0; i < 4; i++)
#pragma unroll
        for (int r = 0; r < 4; r++) {
          int s = s0 + wy * 64 + i * 16 + q * 4 + r;
          short* row = dst + (size_t)s * HD;
#pragma unroll
          for (int jl = 0; jl < 4; jl++)
            row[ctl[jl] * 16 + c] = (short)f2bf(acc[i][jl][r] * 0.08838834764831845f);
        }
    } else {  // K in flash B-operand fragment order [bh][kt][8192]
      short* dst = Kg + (size_t)bh * 16 * 8192 + (size_t)((s0 >> 6) + wy) * 8192;
#pragma unroll
      for (int i = 0; i < 4; i++)
#pragma unroll
        for (int jl = 0; jl < 4; jl++) {
          int ks = ctl[jl] >> 1;
          int qqf = ((ctl[jl] & 1) << 1) + (c >> 3);
          short* p = dst + (ks * 4 + i) * 512 + qqf * 128 + (c & 7);
#pragma unroll
          for (int r = 0; r < 4; r++)
            p[(q * 4 + r) * 8] = (short)f2bf(acc[i][jl][r]);
        }
    }
  } else {  // V in flash B-operand (k = seq) fragment order [bh][kt][8192]
    short* dst = Vg + (size_t)bh * 16 * 8192 + (size_t)((s0 >> 6) + wy) * 8192;
#pragma unroll
    for (int i = 0; i < 4; i++)
#pragma unroll
      for (int jl = 0; jl < 4; jl++)
#pragma unroll
        for (int r = 0; r < 4; r++) {
          int sl = q * 4 + r;
          int qqf = ((i & 1) << 1) + (sl >> 3);
          dst[((i >> 1) * 8 + ctl[jl]) * 512 + qqf * 128 + c * 8 + (sl & 7)] =
              (short)f2bf(acc[i][jl][r]);
        }
  }
}

// ---------------- causal flash attention, q-tile 64, KT 64 ----------------
__global__ __launch_bounds__(256) void flash_attn(
    const short* __restrict__ Qg, const short* __restrict__ Kg,
    const short* __restrict__ Vg, float* __restrict__ out) {
  __shared__ __align__(16) short Ks[8192];
  __shared__ __align__(16) short Vts[8192];
  __shared__ __align__(16) short Ps[4096];  // wave-private 1024-short regions

  const int tid = threadIdx.x;
  const int w = tid >> 6, lane = tid & 63;
  const int q = lane >> 4, c = lane & 15;
  const int bh = blockIdx.x, qt = blockIdx.y;  // XCD = bh%8 -> balanced qt
  const int q0 = qt * 64;

  const short* Qh = Qg + (size_t)bh * S_ * HD;
  const short* Kh = Kg + (size_t)bh * 16 * 8192;
  const short* Vh = Vg + (size_t)bh * 16 * 8192;

  bf16x8 aq[4];  // wave w owns q-rows q0 + w*16 + [0,16)
#pragma unroll
  for (int ks = 0; ks < 4; ks++)
    aq[ks] = *(const bf16x8*)(Qh + (size_t)(q0 + w * 16 + c) * HD + ks * 32 + q * 8);

  f32x4 o[8];
  float m_[4], l_[4];
#pragma unroll
  for (int tj = 0; tj < 8; tj++) o[tj] = (f32x4){0.f, 0.f, 0.f, 0.f};
#pragma unroll
  for (int r = 0; r < 4; r++) { m_[r] = -1e30f; l_[r] = 0.f; }

  for (int it = 0; it <= qt; it++) {
#pragma unroll
    for (int i = 0; i < 4; i++) {
      int ch = i * 256 + tid;
      gl_lds16(Kh + (size_t)it * 8192 + ch * 8, Ks + ch * 8);
      gl_lds16(Vh + (size_t)it * 8192 + ch * 8, Vts + ch * 8);
    }
    __syncthreads();

    f32x4 s[4];
#pragma unroll
    for (int tj = 0; tj < 4; tj++) s[tj] = (f32x4){0.f, 0.f, 0.f, 0.f};
#pragma unroll
    for (int ks = 0; ks < 4; ks++)
#pragma unroll
      for (int tj = 0; tj < 4; tj++) {
        bf16x8 bk = *(const bf16x8*)(Ks + (ks * 4 + tj) * 512 + lane * 8);
        s[tj] = __builtin_amdgcn_mfma_f32_16x16x32_bf16(aq[ks], bk, s[tj], 0, 0, 0);
      }

    if (it == qt) {  // diagonal tile only
#pragma unroll
      for (int tj = 0; tj < 4; tj++) {
        int kj = tj * 16 + c;
#pragma unroll
        for (int r = 0; r < 4; r++)
          if (kj > w * 16 + q * 4 + r) s[tj][r] = -1e30f;
      }
    }

    // online softmax — all cross-lane via DPP (VALU pipe, no ds_bpermute)
#pragma unroll
    for (int r = 0; r < 4; r++) {
      float mx = fmaxf(fmaxf(s[0][r], s[1][r]), fmaxf(s[2][r], s[3][r]));
      mx = red_max16(mx);
      float mn = fmaxf(m_[r], mx);
      float alpha = __expf(m_[r] - mn);
      m_[r] = mn;
      float rs = 0.f;
#pragma unroll
      for (int tj = 0; tj < 4; tj++) {
        float e = __expf(s[tj][r] - mn);
        s[tj][r] = e;
        rs += e;
      }
      rs = red_sum16(rs);
      l_[r] = l_[r] * alpha + rs;
#pragma unroll
      for (int tjd = 0; tjd < 8; tjd++) o[tjd][r] *= alpha;
    }

    // P: C-layout -> wave-private A-layout region (no barrier needed)
#pragma unroll
    for (int tj = 0; tj < 4; tj++) {
      int base = w * 1024 + (tj >> 1) * 512 + (((tj & 1) << 1) + (c >> 3)) * 128 + (c & 7);
#pragma unroll
      for (int r = 0; r < 4; r++)
        Ps[base + (q * 4 + r) * 8] = (short)f2bf(s[tj][r]);
    }

#pragma unroll
    for (int ks2 = 0; ks2 < 2; ks2++) {
      bf16x8 ap = *(const bf16x8*)(Ps + w * 1024 + ks2 * 512 + lane * 8);
#pragma unroll
      for (int tjd = 0; tjd < 8; tjd++) {
        bf16x8 bv = *(const bf16x8*)(Vts + (ks2 * 8 + tjd) * 512 + lane * 8);
        o[tjd] = __builtin_amdgcn_mfma_f32_16x16x32_bf16(ap, bv, o[tjd], 0, 0, 0);
      }
    }
    __syncthreads();  // Ks/Vts consumed before next staging
  }

  const int b = bh >> 4, h = bh & 15;
#pragma unroll
  for (int r = 0; r < 4; r++) {
    float inv = 1.0f / l_[r];
    int sg = q0 + w * 16 + q * 4 + r;
    float* dst = out + (size_t)(b * S_ + sg) * D_ + h * HD;
#pragma unroll
    for (int tjd = 0; tjd < 8; tjd++) dst[tjd * 16 + c] = o[tjd][r] * inv;
  }
}

extern "C" void kernel_launch(void* const* d_in, const int* in_sizes, int n_in,
                              void* d_out, int out_size, void* d_ws, size_t ws_size,
                              hipStream_t stream) {
  (void)in_sizes; (void)n_in; (void)out_size; (void)ws_size;
  const float* hs = (const float*)d_in[0];
  const float* wq = (const float*)d_in[1];
  const float* bq = (const float*)d_in[2];
  char* ws = (char*)d_ws;
  // ws: Xt 16MiB | Wt 24MiB | Qg 16MiB | Kg 16MiB | Vg 16MiB | rope 512KiB
  short* Xt = (short*)(ws);
  short* Wt = (short*)(ws + 16777216);
  short* Qg = (short*)(ws + 41943040);
  short* Kg = (short*)(ws + 58720256);
  short* Vg = (short*)(ws + 75497472);
  float2* tbl = (float2*)(ws + 92274688);

  hipLaunchKernelGGL(cvt_repack, dim3(32 * 64), dim3(256), 0, stream, hs, Xt);
  hipLaunchKernelGGL(cvt_repack, dim3(48 * 64), dim3(256), 0, stream, wq, Wt);
  hipLaunchKernelGGL(rope_tbl, dim3(256), dim3(256), 0, stream, tbl);
  hipLaunchKernelGGL(qkv_gemm, dim3(48, 32), dim3(256), 0, stream, Xt, Wt, bq, tbl, Qg, Kg, Vg);
  hipLaunchKernelGGL(flash_attn, dim3(64, 16), dim3(256), 0, stream, Qg, Kg, Vg, (float*)d_out);
}

// Round 5
// 291.483 us; speedup vs baseline: 1.5704x; 1.0217x over previous
//
#include <hip/hip_runtime.h>
#include <stdint.h>

#define B_ 4
#define S_ 1024
#define D_ 2048
#define H_ 16
#define HD 128
#define E_ 6144

typedef short bf16x8 __attribute__((ext_vector_type(8)));
typedef float f32x4 __attribute__((ext_vector_type(4)));

__device__ __forceinline__ unsigned short f2bf(float f) {
  union { float f; unsigned u; } x; x.f = f;
  unsigned r = x.u + 0x7fffu + ((x.u >> 16) & 1u);
  return (unsigned short)(r >> 16);
}

__device__ __forceinline__ void gl_lds16(const void* g, void* l) {
  __builtin_amdgcn_global_load_lds(
      (const __attribute__((address_space(1))) void*)g,
      (__attribute__((address_space(3))) void*)l, 16, 0, 0);
}

// DPP cross-lane within the 16-lane row: single-cycle VALU, no LDS pipe.
template <int C>
__device__ __forceinline__ float dppf(float x) {
  union { float f; int i; } u; u.f = x;
  u.i = __builtin_amdgcn_update_dpp(u.i, u.i, C, 0xF, 0xF, true);
  return u.f;
}
__device__ __forceinline__ float red_max16(float v) {
  v = fmaxf(v, dppf<0xB1>(v));   // quad_perm [1,0,3,2]  (xor 1)
  v = fmaxf(v, dppf<0x4E>(v));   // quad_perm [2,3,0,1]  (xor 2)
  v = fmaxf(v, dppf<0x124>(v));  // row_ror:4
  v = fmaxf(v, dppf<0x128>(v));  // row_ror:8
  return v;
}
__device__ __forceinline__ float red_sum16(float v) {
  v += dppf<0xB1>(v);
  v += dppf<0x4E>(v);
  v += dppf<0x124>(v);
  v += dppf<0x128>(v);
  return v;
}

// ---- fp32 -> bf16 fragment-tiled cast via LDS repack ----
__global__ __launch_bounds__(256) void cvt_repack(const float* __restrict__ src,
                                                  short* __restrict__ dst) {
  __shared__ __align__(16) short L[128 * 40];
  const int tid = threadIdx.x;
  const int kt = blockIdx.x & 63, mt = blockIdx.x >> 6;
  {
    int row = tid >> 1, half = tid & 1;
    const float* p = src + (size_t)(mt * 128 + row) * D_ + kt * 32 + half * 16;
    float4 v0 = *(const float4*)(p);
    float4 v1 = *(const float4*)(p + 4);
    float4 v2 = *(const float4*)(p + 8);
    float4 v3 = *(const float4*)(p + 12);
    union { short s[16]; int4 v[2]; } u;
    u.s[0] = (short)f2bf(v0.x);  u.s[1] = (short)f2bf(v0.y);
    u.s[2] = (short)f2bf(v0.z);  u.s[3] = (short)f2bf(v0.w);
    u.s[4] = (short)f2bf(v1.x);  u.s[5] = (short)f2bf(v1.y);
    u.s[6] = (short)f2bf(v1.z);  u.s[7] = (short)f2bf(v1.w);
    u.s[8] = (short)f2bf(v2.x);  u.s[9] = (short)f2bf(v2.y);
    u.s[10] = (short)f2bf(v2.z); u.s[11] = (short)f2bf(v2.w);
    u.s[12] = (short)f2bf(v3.x); u.s[13] = (short)f2bf(v3.y);
    u.s[14] = (short)f2bf(v3.z); u.s[15] = (short)f2bf(v3.w);
    int4* lp = (int4*)(L + row * 40 + half * 16);
    lp[0] = u.v[0];
    lp[1] = u.v[1];
  }
  __syncthreads();
  short* out = dst + (((size_t)(mt * 64 + kt)) << 12);
#pragma unroll
  for (int i = 0; i < 2; i++) {
    int ch = i * 256 + tid;
    int cc = ch & 15, qq = (ch >> 4) & 3, rt = ch >> 6;
    int4 v = *(const int4*)(L + (rt * 16 + cc) * 40 + qq * 8);
    *(int4*)(out + ch * 8) = v;
  }
}

// ---------------- RoPE cos/sin table ----------------
__global__ __launch_bounds__(256) void rope_tbl(float2* __restrict__ t) {
  int idx = blockIdx.x * 256 + threadIdx.x;  // 65536
  int s = idx >> 6, j = idx & 63;
  float inv = exp2f(-0.20762050593045953f * (float)j);
  float a = (float)s * inv;
  t[idx] = make_float2(cosf(a), sinf(a));
}

// ---------------- QKV GEMM + bias + RoPE + fragment-order scatter ----------
__global__ __launch_bounds__(256) void qkv_gemm(
    const short* __restrict__ Xt, const short* __restrict__ Wt,
    const float* __restrict__ bq, const float2* __restrict__ rope,
    short* __restrict__ Qg, short* __restrict__ Kg, short* __restrict__ Vg) {
  __shared__ __align__(16) short As[4096];
  __shared__ __align__(16) short Bs[4096];

  const int tid = threadIdx.x;
  const int w = tid >> 6, lane = tid & 63;
  const int q = lane >> 4, c = lane & 15;
  const int wy = w >> 1, wx = w & 1;
  const int bn = blockIdx.x, bm = blockIdx.y;

  const short* Abase = Xt + (size_t)bm * 64 * 4096;
  const short* Bbase = Wt + (size_t)bn * 64 * 4096;

  f32x4 acc[4][4];
#pragma unroll
  for (int i = 0; i < 4; i++)
#pragma unroll
    for (int jl = 0; jl < 4; jl++) acc[i][jl] = (f32x4){0.f, 0.f, 0.f, 0.f};

  for (int kt = 0; kt < 64; kt++) {
    const short* Ak = Abase + (size_t)kt * 4096;
    const short* Bk = Bbase + (size_t)kt * 4096;
#pragma unroll
    for (int i = 0; i < 2; i++) {
      int ch = i * 256 + tid;
      gl_lds16(Ak + ch * 8, As + ch * 8);
      gl_lds16(Bk + ch * 8, Bs + ch * 8);
    }
    __syncthreads();
    bf16x8 a[4], b[4];
#pragma unroll
    for (int i = 0; i < 4; i++)
      a[i] = *(const bf16x8*)(As + (wy * 4 + i) * 512 + lane * 8);
#pragma unroll
    for (int jl = 0; jl < 4; jl++) {
      int ct = 2 * wx + (jl & 1) + ((jl >> 1) << 2);
      b[jl] = *(const bf16x8*)(Bs + ct * 512 + lane * 8);
    }
#pragma unroll
    for (int i = 0; i < 4; i++)
#pragma unroll
      for (int jl = 0; jl < 4; jl++)
        acc[i][jl] = __builtin_amdgcn_mfma_f32_16x16x32_bf16(a[i], b[jl], acc[i][jl], 0, 0, 0);
    __syncthreads();
  }

  const int head = bn / 3, typ = bn - head * 3;
  const int b = bm >> 3;
  const int bh = b * H_ + head;
  const int s0 = (bm & 7) << 7;

  int ctl[4];
  float bias[4];
#pragma unroll
  for (int jl = 0; jl < 4; jl++) {
    ctl[jl] = 2 * wx + (jl & 1) + ((jl >> 1) << 2);
    bias[jl] = bq[bn * 128 + ctl[jl] * 16 + c];
  }
#pragma unroll
  for (int i = 0; i < 4; i++)
#pragma unroll
    for (int jl = 0; jl < 4; jl++)
#pragma unroll
      for (int r = 0; r < 4; r++) acc[i][jl][r] += bias[jl];

  if (typ < 2) {
#pragma unroll
    for (int i = 0; i < 4; i++)
#pragma unroll
      for (int r = 0; r < 4; r++) {
        int s = s0 + wy * 64 + i * 16 + q * 4 + r;
#pragma unroll
        for (int jl = 0; jl < 2; jl++) {
          float2 cs = rope[s * 64 + ctl[jl] * 16 + c];
          float x1 = acc[i][jl][r], x2 = acc[i][jl + 2][r];
          acc[i][jl][r] = x1 * cs.x - x2 * cs.y;
          acc[i][jl + 2][r] = x2 * cs.x + x1 * cs.y;
        }
      }
    if (typ == 0) {
      short* dst = Qg + (size_t)bh * S_ * HD;
#pragma unroll
      for (int i = 0; i < 4; i++)
#pragma unroll
        for (int r = 0; r < 4; r++) {
          int s = s0 + wy * 64 + i * 16 + q * 4 + r;
          short* row = dst + (size_t)s * HD;
#pragma unroll
          for (int jl = 0; jl < 4; jl++)
            row[ctl[jl] * 16 + c] = (short)f2bf(acc[i][jl][r] * 0.08838834764831845f);
        }
    } else {
      short* dst = Kg + (size_t)bh * 16 * 8192 + (size_t)((s0 >> 6) + wy) * 8192;
#pragma unroll
      for (int i = 0; i < 4; i++)
#pragma unroll
        for (int jl = 0; jl < 4; jl++) {
          int ks = ctl[jl] >> 1;
          int qqf = ((ctl[jl] & 1) << 1) + (c >> 3);
          short* p = dst + (ks * 4 + i) * 512 + qqf * 128 + (c & 7);
#pragma unroll
          for (int r = 0; r < 4; r++)
            p[(q * 4 + r) * 8] = (short)f2bf(acc[i][jl][r]);
        }
    }
  } else {
    short* dst = Vg + (size_t)bh * 16 * 8192 + (size_t)((s0 >> 6) + wy) * 8192;
#pragma unroll
    for (int i = 0; i < 4; i++)
#pragma unroll
      for (int jl = 0; jl < 4; jl++)
#pragma unroll
        for (int r = 0; r < 4; r++) {
          int sl = q * 4 + r;
          int qqf = ((i & 1) << 1) + (sl >> 3);
          dst[((i >> 1) * 8 + ctl[jl]) * 512 + qqf * 128 + c * 8 + (sl & 7)] =
              (short)f2bf(acc[i][jl][r]);
        }
  }
}

// ---------------- causal flash attention ----------------
// Paired q-tiles (p, 15-p): every block does exactly 17 tile-iterations.
// K double-buffered; manual s_waitcnt vmcnt(N) + raw s_barrier pipelining.
__global__ __launch_bounds__(256) void flash_attn(
    const short* __restrict__ Qg, const short* __restrict__ Kg,
    const short* __restrict__ Vg, float* __restrict__ out) {
  __shared__ __align__(16) short Kb[2][8192];  // 32 KB
  __shared__ __align__(16) short Vb[8192];     // 16 KB
  __shared__ __align__(16) short Ps[4096];     // 8 KB, wave-private 1 KB regions

  const int tid = threadIdx.x;
  const int w = tid >> 6, lane = tid & 63;
  const int q = lane >> 4, c = lane & 15;
  const int bh = blockIdx.x, p = blockIdx.y;  // XCD = bh%8 -> balanced
  const int b = bh >> 4, h = bh & 15;

  const short* Qh = Qg + (size_t)bh * S_ * HD;
  const short* Kh = Kg + (size_t)bh * 16 * 8192;
  const short* Vh = Vg + (size_t)bh * 16 * 8192;

#pragma unroll
  for (int ph = 0; ph < 2; ph++) {
    const int qt = ph ? 15 - p : p;
    const int q0 = qt * 64;
    const int n = qt + 1;

    bf16x8 aq[4];
#pragma unroll
    for (int ks = 0; ks < 4; ks++)
      aq[ks] = *(const bf16x8*)(Qh + (size_t)(q0 + w * 16 + c) * HD + ks * 32 + q * 8);

    f32x4 o[8];
    float m_[4], l_[4];
#pragma unroll
    for (int tj = 0; tj < 8; tj++) o[tj] = (f32x4){0.f, 0.f, 0.f, 0.f};
#pragma unroll
    for (int r = 0; r < 4; r++) { m_[r] = -1e30f; l_[r] = 0.f; }

    // pre-stage: K0 (4 instr/thread), then V0 (4 instr/thread)
#pragma unroll
    for (int i = 0; i < 4; i++) {
      int ch = i * 256 + tid;
      gl_lds16(Kh + ch * 8, &Kb[0][ch * 8]);
    }
#pragma unroll
    for (int i = 0; i < 4; i++) {
      int ch = i * 256 + tid;
      gl_lds16(Vh + ch * 8, Vb + ch * 8);
    }

    for (int it = 0; it < n; it++) {
      const int cur = it & 1;
      // wait K(it): all but the 4 newest (V(it) or K-prefetch) drained
      asm volatile("s_waitcnt vmcnt(4)" ::: "memory");
      __builtin_amdgcn_s_barrier();  // B1: K(it) visible to all waves

      f32x4 s[4];
#pragma unroll
      for (int tj = 0; tj < 4; tj++) s[tj] = (f32x4){0.f, 0.f, 0.f, 0.f};
#pragma unroll
      for (int ks = 0; ks < 4; ks++)
#pragma unroll
        for (int tj = 0; tj < 4; tj++) {
          bf16x8 bk = *(const bf16x8*)(&Kb[cur][(ks * 4 + tj) * 512 + lane * 8]);
          s[tj] = __builtin_amdgcn_mfma_f32_16x16x32_bf16(aq[ks], bk, s[tj], 0, 0, 0);
        }

      // prefetch K(it+1) into the other buffer (its last reader finished
      // before B2 of it-1 < B1 of it)
      if (it + 1 < n) {
#pragma unroll
        for (int i = 0; i < 4; i++) {
          int ch = i * 256 + tid;
          gl_lds16(Kh + (size_t)(it + 1) * 8192 + ch * 8, &Kb[cur ^ 1][ch * 8]);
        }
      }

      if (it == qt) {  // diagonal tile: causal mask
#pragma unroll
        for (int tj = 0; tj < 4; tj++) {
          int kj = tj * 16 + c;
#pragma unroll
          for (int r = 0; r < 4; r++)
            if (kj > w * 16 + q * 4 + r) s[tj][r] = -1e30f;
        }
      }

      // online softmax (DPP reductions within the 16-lane col group)
#pragma unroll
      for (int r = 0; r < 4; r++) {
        float mx = fmaxf(fmaxf(s[0][r], s[1][r]), fmaxf(s[2][r], s[3][r]));
        mx = red_max16(mx);
        float mn = fmaxf(m_[r], mx);
        float alpha = __expf(m_[r] - mn);
        m_[r] = mn;
        float rs = 0.f;
#pragma unroll
        for (int tj = 0; tj < 4; tj++) {
          float e = __expf(s[tj][r] - mn);
          s[tj][r] = e;
          rs += e;
        }
        rs = red_sum16(rs);
        l_[r] = l_[r] * alpha + rs;
#pragma unroll
        for (int tjd = 0; tjd < 8; tjd++) o[tjd][r] *= alpha;
      }

      // wait V(it): only the K-prefetch (4) may remain in flight
      if (it + 1 < n)
        asm volatile("s_waitcnt vmcnt(4)" ::: "memory");
      else
        asm volatile("s_waitcnt vmcnt(0)" ::: "memory");
      __builtin_amdgcn_s_barrier();  // B2: V(it) visible to all waves

      // P: C-layout -> wave-private A-layout region
#pragma unroll
      for (int tj = 0; tj < 4; tj++) {
        int base = w * 1024 + (tj >> 1) * 512 + (((tj & 1) << 1) + (c >> 3)) * 128 + (c & 7);
#pragma unroll
        for (int r = 0; r < 4; r++)
          Ps[base + (q * 4 + r) * 8] = (short)f2bf(s[tj][r]);
      }

#pragma unroll
      for (int ks2 = 0; ks2 < 2; ks2++) {
        bf16x8 ap = *(const bf16x8*)(Ps + w * 1024 + ks2 * 512 + lane * 8);
#pragma unroll
        for (int tjd = 0; tjd < 8; tjd++) {
          bf16x8 bv = *(const bf16x8*)(Vb + (ks2 * 8 + tjd) * 512 + lane * 8);
          o[tjd] = __builtin_amdgcn_mfma_f32_16x16x32_bf16(ap, bv, o[tjd], 0, 0, 0);
        }
      }
      __builtin_amdgcn_s_barrier();  // B3: all waves done reading Vb

      // stage V(it+1); its wait is B2 of it+1 (overlapped by QK+softmax)
      if (it + 1 < n) {
#pragma unroll
        for (int i = 0; i < 4; i++) {
          int ch = i * 256 + tid;
          gl_lds16(Vh + (size_t)(it + 1) * 8192 + ch * 8, Vb + ch * 8);
        }
      }
    }

#pragma unroll
    for (int r = 0; r < 4; r++) {
      float inv = 1.0f / l_[r];
      int sg = q0 + w * 16 + q * 4 + r;
      float* dst = out + (size_t)(b * S_ + sg) * D_ + h * HD;
#pragma unroll
      for (int tjd = 0; tjd < 8; tjd++) dst[tjd * 16 + c] = o[tjd][r] * inv;
    }
    // phase ends with zero outstanding loads (last iter stages nothing)
  }
}

extern "C" void kernel_launch(void* const* d_in, const int* in_sizes, int n_in,
                              void* d_out, int out_size, void* d_ws, size_t ws_size,
                              hipStream_t stream) {
  (void)in_sizes; (void)n_in; (void)out_size; (void)ws_size;
  const float* hs = (const float*)d_in[0];
  const float* wq = (const float*)d_in[1];
  const float* bq = (const float*)d_in[2];
  char* ws = (char*)d_ws;
  short* Xt = (short*)(ws);
  short* Wt = (short*)(ws + 16777216);
  short* Qg = (short*)(ws + 41943040);
  short* Kg = (short*)(ws + 58720256);
  short* Vg = (short*)(ws + 75497472);
  float2* tbl = (float2*)(ws + 92274688);

  hipLaunchKernelGGL(cvt_repack, dim3(32 * 64), dim3(256), 0, stream, hs, Xt);
  hipLaunchKernelGGL(cvt_repack, dim3(48 * 64), dim3(256), 0, stream, wq, Wt);
  hipLaunchKernelGGL(rope_tbl, dim3(256), dim3(256), 0, stream, tbl);
  hipLaunchKernelGGL(qkv_gemm, dim3(48, 32), dim3(256), 0, stream, Xt, Wt, bq, tbl, Qg, Kg, Vg);
  hipLaunchKernelGGL(flash_attn, dim3(64, 8), dim3(256), 0, stream, Qg, Kg, Vg, (float*)d_out);
}